// Round 2
// baseline (12093.200 us; speedup 1.0000x reference)
//
#include <hip/hip_runtime.h>
#include <hip/hip_bf16.h>

#define SEQ 512
#define BATCH 64
#define HID 1024

typedef __bf16 bf16x8 __attribute__((ext_vector_type(8)));
typedef __bf16 bf16x4 __attribute__((ext_vector_type(4)));
typedef float f32x4 __attribute__((ext_vector_type(4)));

__device__ __forceinline__ float sigm(float x) { return 1.0f / (1.0f + __expf(-x)); }
__device__ __forceinline__ float tanh_(float x) { return 2.0f / (1.0f + __expf(-2.0f * x)) - 1.0f; }

// ---------------------------------------------------------------------------
// f32 -> bf16 conversion (n multiple of 4)
// ---------------------------------------------------------------------------
__global__ __launch_bounds__(256) void cvt_f32_bf16(const float* __restrict__ src,
                                                     __bf16* __restrict__ dst, int n)
{
    int i = (blockIdx.x * 256 + threadIdx.x) * 4;
    if (i < n) {
        f32x4 v = *(const f32x4*)(src + i);
        bf16x4 o;
        #pragma unroll
        for (int j = 0; j < 4; ++j) o[j] = (__bf16)v[j];
        *(bf16x4*)(dst + i) = o;
    }
}

// ---------------------------------------------------------------------------
// Phase A: G[m][n], m = t*BATCH+b, n in [0,3072):
//   n in [0,1024):    x_m @ W_r[:, :1024].T + b_r
//   n in [1024,2048): x_m @ W_u[:, :1024].T + b_u
//   n in [2048,3072): x_m @ W_x.T + b_x
// Tile: 128(M) x 64(N) per WG, 4 waves 2x2, MFMA 16x16x32 bf16.
// XB: x pre-converted to bf16 in ws (else convert f32 on the fly).
// ---------------------------------------------------------------------------
template <bool XB>
__global__ __launch_bounds__(256) void gru_phaseA(
    const float* __restrict__ xf, const __bf16* __restrict__ xb,
    const __bf16* __restrict__ Wrb, const __bf16* __restrict__ Wub,
    const __bf16* __restrict__ Wxb,
    const float* __restrict__ br, const float* __restrict__ bu,
    const float* __restrict__ bx, __bf16* __restrict__ G)
{
    const int NT = (3 * HID) / 64;  // 48 n-tiles, never crossing a matrix boundary
    int mt = blockIdx.x / NT;
    int nt = blockIdx.x % NT;
    int m0 = mt * 128, n0 = nt * 64;

    const __bf16* W; const float* bias; int wstride, nb;
    if (n0 < HID)          { W = Wrb; bias = br; wstride = 2 * HID; nb = n0; }
    else if (n0 < 2 * HID) { W = Wub; bias = bu; wstride = 2 * HID; nb = n0 - HID; }
    else                   { W = Wxb; bias = bx; wstride = HID;     nb = n0 - 2 * HID; }

    int lane = threadIdx.x & 63, w = threadIdx.x >> 6;
    int llo = lane & 15, lhi = lane >> 4;
    int wm = (w & 1) * 64, wn = (w >> 1) * 32;

    f32x4 acc[4][2] = {};
    #pragma unroll 2
    for (int k0 = 0; k0 < HID; k0 += 32) {
        int ka = k0 + lhi * 8;
        bf16x8 af[4], bfr[2];
        #pragma unroll
        for (int mi = 0; mi < 4; ++mi) {
            size_t roff = (size_t)(m0 + wm + mi * 16 + llo) * HID + ka;
            if (XB) {
                af[mi] = *(const bf16x8*)(xb + roff);
            } else {
                f32x4 lo = *(const f32x4*)(xf + roff);
                f32x4 hi = *(const f32x4*)(xf + roff + 4);
                #pragma unroll
                for (int j = 0; j < 4; ++j) { af[mi][j] = (__bf16)lo[j]; af[mi][4 + j] = (__bf16)hi[j]; }
            }
        }
        #pragma unroll
        for (int ni = 0; ni < 2; ++ni)
            bfr[ni] = *(const bf16x8*)(W + (size_t)(nb + wn + ni * 16 + llo) * wstride + ka);
        #pragma unroll
        for (int mi = 0; mi < 4; ++mi)
            #pragma unroll
            for (int ni = 0; ni < 2; ++ni)
                acc[mi][ni] = __builtin_amdgcn_mfma_f32_16x16x32_bf16(af[mi], bfr[ni], acc[mi][ni], 0, 0, 0);
    }
    #pragma unroll
    for (int ni = 0; ni < 2; ++ni) {
        int colg = n0 + wn + ni * 16 + llo;
        float bv = bias[nb + wn + ni * 16 + llo];
        #pragma unroll
        for (int mi = 0; mi < 4; ++mi) {
            #pragma unroll
            for (int i = 0; i < 4; ++i) {
                int row = m0 + wm + mi * 16 + lhi * 4 + i;
                G[(size_t)row * (3 * HID) + colg] = (__bf16)(acc[mi][ni][i] + bv);
            }
        }
    }
}

// ---------------------------------------------------------------------------
// Init: h0 = prev_state (fp32 master + bf16 copy), zero the barrier counter.
// ---------------------------------------------------------------------------
__global__ __launch_bounds__(256) void gru_init(const float* __restrict__ prev,
                                                float* __restrict__ hf, __bf16* __restrict__ hb,
                                                unsigned* __restrict__ cnt)
{
    int i = blockIdx.x * 256 + threadIdx.x;
    if (i == 0) *cnt = 0u;
    if (i < BATCH * HID) { float v = prev[i]; hf[i] = v; hb[i] = (__bf16)v; }
}

// ---------------------------------------------------------------------------
// Phase B: persistent recurrent kernel. 64 WGs (co-resident: 64 <= 256 CUs),
// WG j owns hidden cols [16j,16j+16); wave w owns batch rows [16w,16w+16).
// Step barrier = monotonic global counter (release fence -> atomicAdd ->
// relaxed spin -> acquire fence).
// ---------------------------------------------------------------------------
__global__ __launch_bounds__(256) void gru_phaseB(
    const __bf16* __restrict__ Wrb, const __bf16* __restrict__ Wub,
    const __bf16* __restrict__ Wob, const float* __restrict__ bo,
    const __bf16* __restrict__ G,
    float* __restrict__ hf, __bf16* __restrict__ hb, unsigned* __restrict__ cnt,
    float* __restrict__ out)
{
    int j = blockIdx.x;  // 0..63
    int lane = threadIdx.x & 63, w = threadIdx.x >> 6;
    int llo = lane & 15, lhi = lane >> 4;
    int col = 16 * j + llo;
    const __bf16* wrr = Wrb + (size_t)col * (2 * HID) + HID;  // h-part of W_r row
    const __bf16* wur = Wub + (size_t)col * (2 * HID) + HID;  // h-part of W_u row
    const __bf16* wor = Wob + (size_t)col * HID;
    float bov = bo[col];
    const unsigned nWG = gridDim.x;

    for (int t = 0; t < SEQ; ++t) {
        int cur = t & 1, nxt = cur ^ 1;
        const __bf16* h = hb + cur * (BATCH * HID);
        f32x4 aR = {}, aU = {}, aO = {};
        #pragma unroll 4
        for (int k0 = 0; k0 < HID; k0 += 32) {
            int ka = k0 + lhi * 8;
            bf16x8 af = *(const bf16x8*)(h + (size_t)(16 * w + llo) * HID + ka);
            bf16x8 bR = *(const bf16x8*)(wrr + ka);
            bf16x8 bU = *(const bf16x8*)(wur + ka);
            bf16x8 bO = *(const bf16x8*)(wor + ka);
            aR = __builtin_amdgcn_mfma_f32_16x16x32_bf16(af, bR, aR, 0, 0, 0);
            aU = __builtin_amdgcn_mfma_f32_16x16x32_bf16(af, bU, aU, 0, 0, 0);
            aO = __builtin_amdgcn_mfma_f32_16x16x32_bf16(af, bO, aO, 0, 0, 0);
        }
        const __bf16* Gt = G + (size_t)t * BATCH * (3 * HID);
        #pragma unroll
        for (int i = 0; i < 4; ++i) {
            int row = 16 * w + lhi * 4 + i;
            size_t gbase = (size_t)row * (3 * HID) + 16 * j + llo;
            float gr = (float)Gt[gbase];
            float gu = (float)Gt[gbase + HID];
            float gx = (float)Gt[gbase + 2 * HID];
            float r = sigm(aR[i] + gr);
            float u = sigm(aU[i] + gu);
            float c = tanh_((aO[i] + bov) * r + gx);
            size_t hidx = (size_t)row * HID + 16 * j + llo;
            float hold = hf[cur * (BATCH * HID) + hidx];
            float hnew = (1.0f - u) * c + u * hold;
            hf[nxt * (BATCH * HID) + hidx] = hnew;
            hb[nxt * (BATCH * HID) + hidx] = (__bf16)hnew;
            out[(size_t)t * (BATCH * HID) + hidx] = hnew;
            if (t == SEQ - 1) out[(size_t)SEQ * (BATCH * HID) + hidx] = hnew;
        }
        // ---- grid step-barrier ----
        __syncthreads();                  // drain this WG's stores
        if (threadIdx.x == 0) {
            __threadfence();              // release (device scope, cross-XCD L2 writeback)
            atomicAdd(cnt, 1u);
            unsigned target = nWG * (unsigned)(t + 1);
            int guard = 0;
            while (__hip_atomic_load(cnt, __ATOMIC_RELAXED, __HIP_MEMORY_SCOPE_AGENT) < target
                   && ++guard < (1 << 20)) {
                __builtin_amdgcn_s_sleep(2);
            }
            __threadfence();              // acquire (invalidate stale caches)
        }
        __syncthreads();
    }
}

extern "C" void kernel_launch(void* const* d_in, const int* in_sizes, int n_in,
                              void* d_out, int out_size, void* d_ws, size_t ws_size,
                              hipStream_t stream) {
    (void)in_sizes; (void)n_in; (void)out_size;
    const float* x    = (const float*)d_in[0];
    const float* prev = (const float*)d_in[1];
    const float* Wr   = (const float*)d_in[2];
    const float* br   = (const float*)d_in[3];
    const float* Wu   = (const float*)d_in[4];
    const float* bu   = (const float*)d_in[5];
    const float* Wo   = (const float*)d_in[6];
    const float* bo   = (const float*)d_in[7];
    const float* Wx   = (const float*)d_in[8];
    const float* bx   = (const float*)d_in[9];
    float* out = (float*)d_out;

    // workspace layout (bytes)
    const size_t G_ELEMS  = (size_t)SEQ * BATCH * 3 * HID;   // 100663296
    const size_t WR_ELEMS = (size_t)HID * 2 * HID;           // 2097152
    const size_t WO_ELEMS = (size_t)HID * HID;               // 1048576
    char* ws = (char*)d_ws;
    size_t off = 0;
    __bf16* G   = (__bf16*)(ws + off); off += G_ELEMS * 2;
    __bf16* Wrb = (__bf16*)(ws + off); off += WR_ELEMS * 2;
    __bf16* Wub = (__bf16*)(ws + off); off += WR_ELEMS * 2;
    __bf16* Wob = (__bf16*)(ws + off); off += WO_ELEMS * 2;
    __bf16* Wxb = (__bf16*)(ws + off); off += WO_ELEMS * 2;
    float*  hf  = (float*)(ws + off);  off += (size_t)2 * BATCH * HID * 4;
    __bf16* hb  = (__bf16*)(ws + off); off += (size_t)2 * BATCH * HID * 2;
    unsigned* cnt = (unsigned*)(ws + off); off += 256;
    const size_t X_ELEMS = (size_t)SEQ * BATCH * HID;        // 33554432
    bool use_xb = (ws_size >= off + X_ELEMS * 2);
    __bf16* xb = (__bf16*)(ws + off);

    // conversions
    cvt_f32_bf16<<<(int)(WR_ELEMS / 4 / 256), 256, 0, stream>>>(Wr, Wrb, (int)WR_ELEMS);
    cvt_f32_bf16<<<(int)(WR_ELEMS / 4 / 256), 256, 0, stream>>>(Wu, Wub, (int)WR_ELEMS);
    cvt_f32_bf16<<<(int)(WO_ELEMS / 4 / 256), 256, 0, stream>>>(Wo, Wob, (int)WO_ELEMS);
    cvt_f32_bf16<<<(int)(WO_ELEMS / 4 / 256), 256, 0, stream>>>(Wx, Wxb, (int)WO_ELEMS);
    if (use_xb)
        cvt_f32_bf16<<<(int)(X_ELEMS / 4 / 256), 256, 0, stream>>>(x, xb, (int)X_ELEMS);

    gru_init<<<(BATCH * HID) / 256, 256, 0, stream>>>(prev, hf, hb, cnt);

    int gridA = (SEQ * BATCH / 128) * ((3 * HID) / 64);
    if (use_xb)
        gru_phaseA<true><<<gridA, 256, 0, stream>>>(x, xb, Wrb, Wub, Wxb, br, bu, bx, G);
    else
        gru_phaseA<false><<<gridA, 256, 0, stream>>>(x, xb, Wrb, Wub, Wxb, br, bu, bx, G);

    gru_phaseB<<<HID / 16, 256, 0, stream>>>(Wrb, Wub, Wob, bo, G, hf, hb, cnt, out);
}

// Round 3
// 9216.824 us; speedup vs baseline: 1.3121x; 1.3121x over previous
//
#include <hip/hip_runtime.h>
#include <hip/hip_bf16.h>

#define SEQ 512
#define BATCH 64
#define HID 1024

typedef __bf16 bf16x8 __attribute__((ext_vector_type(8)));
typedef __bf16 bf16x4 __attribute__((ext_vector_type(4)));
typedef float f32x4 __attribute__((ext_vector_type(4)));

__device__ __forceinline__ float sigm(float x) { return 1.0f / (1.0f + __expf(-x)); }
__device__ __forceinline__ float tanh_(float x) { return 2.0f / (1.0f + __expf(-2.0f * x)) - 1.0f; }

// ---------------------------------------------------------------------------
// f32 -> bf16 conversion (n multiple of 4)
// ---------------------------------------------------------------------------
__global__ __launch_bounds__(256) void cvt_f32_bf16(const float* __restrict__ src,
                                                     __bf16* __restrict__ dst, int n)
{
    int i = (blockIdx.x * 256 + threadIdx.x) * 4;
    if (i < n) {
        f32x4 v = *(const f32x4*)(src + i);
        bf16x4 o;
        #pragma unroll
        for (int j = 0; j < 4; ++j) o[j] = (__bf16)v[j];
        *(bf16x4*)(dst + i) = o;
    }
}

// ---------------------------------------------------------------------------
// Phase A (unchanged from round 2): G[m][n] = x-parts of gates, m=t*BATCH+b.
// ---------------------------------------------------------------------------
template <bool XB>
__global__ __launch_bounds__(256) void gru_phaseA(
    const float* __restrict__ xf, const __bf16* __restrict__ xb,
    const __bf16* __restrict__ Wrb, const __bf16* __restrict__ Wub,
    const __bf16* __restrict__ Wxb,
    const float* __restrict__ br, const float* __restrict__ bu,
    const float* __restrict__ bx, __bf16* __restrict__ G)
{
    const int NT = (3 * HID) / 64;
    int mt = blockIdx.x / NT;
    int nt = blockIdx.x % NT;
    int m0 = mt * 128, n0 = nt * 64;

    const __bf16* W; const float* bias; int wstride, nb;
    if (n0 < HID)          { W = Wrb; bias = br; wstride = 2 * HID; nb = n0; }
    else if (n0 < 2 * HID) { W = Wub; bias = bu; wstride = 2 * HID; nb = n0 - HID; }
    else                   { W = Wxb; bias = bx; wstride = HID;     nb = n0 - 2 * HID; }

    int lane = threadIdx.x & 63, w = threadIdx.x >> 6;
    int llo = lane & 15, lhi = lane >> 4;
    int wm = (w & 1) * 64, wn = (w >> 1) * 32;

    f32x4 acc[4][2] = {};
    #pragma unroll 2
    for (int k0 = 0; k0 < HID; k0 += 32) {
        int ka = k0 + lhi * 8;
        bf16x8 af[4], bfr[2];
        #pragma unroll
        for (int mi = 0; mi < 4; ++mi) {
            size_t roff = (size_t)(m0 + wm + mi * 16 + llo) * HID + ka;
            if (XB) {
                af[mi] = *(const bf16x8*)(xb + roff);
            } else {
                f32x4 lo = *(const f32x4*)(xf + roff);
                f32x4 hi = *(const f32x4*)(xf + roff + 4);
                #pragma unroll
                for (int jj = 0; jj < 4; ++jj) { af[mi][jj] = (__bf16)lo[jj]; af[mi][4 + jj] = (__bf16)hi[jj]; }
            }
        }
        #pragma unroll
        for (int ni = 0; ni < 2; ++ni)
            bfr[ni] = *(const bf16x8*)(W + (size_t)(nb + wn + ni * 16 + llo) * wstride + ka);
        #pragma unroll
        for (int mi = 0; mi < 4; ++mi)
            #pragma unroll
            for (int ni = 0; ni < 2; ++ni)
                acc[mi][ni] = __builtin_amdgcn_mfma_f32_16x16x32_bf16(af[mi], bfr[ni], acc[mi][ni], 0, 0, 0);
    }
    #pragma unroll
    for (int ni = 0; ni < 2; ++ni) {
        int colg = n0 + wn + ni * 16 + llo;
        float bv = bias[nb + wn + ni * 16 + llo];
        #pragma unroll
        for (int mi = 0; mi < 4; ++mi) {
            #pragma unroll
            for (int i = 0; i < 4; ++i) {
                int row = m0 + wm + mi * 16 + lhi * 4 + i;
                G[(size_t)row * (3 * HID) + colg] = (__bf16)(acc[mi][ni][i] + bv);
            }
        }
    }
}

// ---------------------------------------------------------------------------
// Init: hg[0] = bf16(prev), zero barrier counter.
// ---------------------------------------------------------------------------
__global__ __launch_bounds__(256) void gru_init(const float* __restrict__ prev,
                                                __bf16* __restrict__ hg,
                                                unsigned* __restrict__ cnt)
{
    int i = blockIdx.x * 256 + threadIdx.x;
    if (i == 0) *cnt = 0u;
    if (i < BATCH * HID) hg[i] = (__bf16)prev[i];
}

// ---------------------------------------------------------------------------
// Phase B v2: persistent recurrent kernel.
// 64 WGs x 768 threads (12 waves). WG j owns hidden cols [16j,16j+16).
// - Weights (h-parts of W_r,W_u + W_o rows for those 16 cols) live in LDS,
//   staged once, XOR-swizzled (T2) to kill the 16-way ds_read_b128 conflict.
// - 12 compute waves = 4 row-groups x 3 gates, each full-K matvec -> LDS gbuf.
// - h fp32 master in LDS (4KB); only bf16 h crosses WGs via global ping-pong.
// - out writes + G(t+1) prefetch deferred to overlap the barrier spin.
// LDS: 96KB weights + 12KB gbuf + 4KB hm = 112KB -> 1 WG/CU.
// ---------------------------------------------------------------------------
__global__ __launch_bounds__(768) void gru_phaseB(
    const __bf16* __restrict__ Wrb, const __bf16* __restrict__ Wub,
    const __bf16* __restrict__ Wob, const float* __restrict__ bo,
    const float* __restrict__ prev, const __bf16* __restrict__ G,
    __bf16* __restrict__ hg, unsigned* __restrict__ cnt,
    float* __restrict__ out)
{
    extern __shared__ char smem[];
    __bf16* Wl   = (__bf16*)smem;                          // [48][1024] swizzled
    float*  gbuf = (float*)(smem + 48 * 1024 * 2);         // [3][4][64][4]
    float*  hm   = (float*)(smem + 48 * 1024 * 2 + 12288); // [64][16]

    const int j = blockIdx.x;           // 0..63
    const int tid = threadIdx.x;
    const int lane = tid & 63, w = tid >> 6;
    const int llo = lane & 15, lhi = lane >> 4;
    const unsigned nWG = gridDim.x;

    // ---- stage weights into LDS (once), XOR-swizzled ----
    {
        int R = tid >> 4;            // 0..47  (gate*16 + col-within-16)
        int seg = tid & 15;          // 0..15
        int gg = R >> 4, c = R & 15;
        const __bf16* src;
        if (gg == 0)      src = Wrb + (size_t)(16 * j + c) * (2 * HID) + HID;
        else if (gg == 1) src = Wub + (size_t)(16 * j + c) * (2 * HID) + HID;
        else              src = Wob + (size_t)(16 * j + c) * HID;
        #pragma unroll
        for (int q = 0; q < 8; ++q) {
            int k = seg * 64 + q * 8;
            bf16x8 v = *(const bf16x8*)(src + k);
            int byte = R * 2048 + k * 2;
            byte ^= ((R & 7) << 4);
            *(bf16x8*)((char*)Wl + byte) = v;
        }
    }
    // ---- init h fp32 master (this WG's 16 cols) ----
    for (int m = tid; m < BATCH * 16; m += 768) {
        int r = m >> 4, c = m & 15;
        hm[m] = prev[(size_t)r * HID + 16 * j + c];
    }
    __syncthreads();

    // combine-wave state (waves 0..3)
    float bov = 0.f;
    float pr[4], pu[4], px[4], outv[4];
    if (w < 4) {
        bov = bo[16 * j + llo];
        #pragma unroll
        for (int i = 0; i < 4; ++i) {
            int row = 16 * w + lhi * 4 + i;
            const __bf16* Gp = G + (size_t)row * (3 * HID) + 16 * j + llo;
            pr[i] = (float)Gp[0]; pu[i] = (float)Gp[HID]; px[i] = (float)Gp[2 * HID];
        }
    }

    const int gg = w >> 2, rg = w & 3;   // compute-wave role (w<12)

    for (int t = 0; t < SEQ; ++t) {
        const __bf16* hcur = hg + (size_t)(t & 1) * (BATCH * HID);
        __bf16* hnxt = hg + (size_t)((t + 1) & 1) * (BATCH * HID);

        if (w < 12) {
            f32x4 a0 = {}, a1 = {};
            const int wbase = (gg * 16 + llo) * 2048;
            const int swz = ((llo & 7) << 4);
            #pragma unroll 8
            for (int it = 0; it < 32; ++it) {
                int ka = it * 32 + lhi * 8;
                bf16x8 af = *(const bf16x8*)(hcur + (size_t)(16 * rg + llo) * HID + ka);
                int byte = (wbase + ka * 2) ^ swz;
                bf16x8 bw = *(const bf16x8*)((const char*)Wl + byte);
                if (it & 1) a1 = __builtin_amdgcn_mfma_f32_16x16x32_bf16(af, bw, a1, 0, 0, 0);
                else        a0 = __builtin_amdgcn_mfma_f32_16x16x32_bf16(af, bw, a0, 0, 0, 0);
            }
            f32x4 a = a0 + a1;
            *(f32x4*)(gbuf + ((gg * 4 + rg) * 64 + lane) * 4) = a;
        }
        __syncthreads();

        if (w < 4) {
            f32x4 aR = *(const f32x4*)(gbuf + ((0 * 4 + w) * 64 + lane) * 4);
            f32x4 aU = *(const f32x4*)(gbuf + ((1 * 4 + w) * 64 + lane) * 4);
            f32x4 aO = *(const f32x4*)(gbuf + ((2 * 4 + w) * 64 + lane) * 4);
            #pragma unroll
            for (int i = 0; i < 4; ++i) {
                int row = 16 * w + lhi * 4 + i;
                float r = sigm(aR[i] + pr[i]);
                float u = sigm(aU[i] + pu[i]);
                float c = tanh_((aO[i] + bov) * r + px[i]);
                float hold = hm[row * 16 + llo];
                float hnew = (1.0f - u) * c + u * hold;
                hm[row * 16 + llo] = hnew;
                hnxt[(size_t)row * HID + 16 * j + llo] = (__bf16)hnew;
                outv[i] = hnew;
            }
        }
        __syncthreads();                  // drain hnxt stores (vmcnt0) + hm/gbuf ordering
        if (tid == 0) {
            __threadfence();              // release: push WG's h writes to device scope
            atomicAdd(cnt, 1u);
        }
        // ---- deferred, overlapped with spin: out writes + G(t+1) prefetch ----
        if (w < 4) {
            #pragma unroll
            for (int i = 0; i < 4; ++i) {
                int row = 16 * w + lhi * 4 + i;
                out[(size_t)t * (BATCH * HID) + (size_t)row * HID + 16 * j + llo] = outv[i];
                if (t == SEQ - 1)
                    out[(size_t)SEQ * (BATCH * HID) + (size_t)row * HID + 16 * j + llo] = outv[i];
            }
            if (t + 1 < SEQ) {
                const __bf16* Gt = G + (size_t)(t + 1) * BATCH * (3 * HID);
                #pragma unroll
                for (int i = 0; i < 4; ++i) {
                    int row = 16 * w + lhi * 4 + i;
                    const __bf16* Gp = Gt + (size_t)row * (3 * HID) + 16 * j + llo;
                    pr[i] = (float)Gp[0]; pu[i] = (float)Gp[HID]; px[i] = (float)Gp[2 * HID];
                }
            }
        }
        if (tid == 0) {
            unsigned target = nWG * (unsigned)(t + 1);
            int guard = 0;
            while (__hip_atomic_load(cnt, __ATOMIC_RELAXED, __HIP_MEMORY_SCOPE_AGENT) < target
                   && ++guard < (1 << 20)) {
                __builtin_amdgcn_s_sleep(1);
            }
            __threadfence();              // acquire: invalidate stale caches
        }
        __syncthreads();
    }
}

extern "C" void kernel_launch(void* const* d_in, const int* in_sizes, int n_in,
                              void* d_out, int out_size, void* d_ws, size_t ws_size,
                              hipStream_t stream) {
    (void)in_sizes; (void)n_in; (void)out_size;
    const float* x    = (const float*)d_in[0];
    const float* prev = (const float*)d_in[1];
    const float* Wr   = (const float*)d_in[2];
    const float* br   = (const float*)d_in[3];
    const float* Wu   = (const float*)d_in[4];
    const float* bu   = (const float*)d_in[5];
    const float* Wo   = (const float*)d_in[6];
    const float* bo   = (const float*)d_in[7];
    const float* Wx   = (const float*)d_in[8];
    const float* bx   = (const float*)d_in[9];
    float* out = (float*)d_out;

    // workspace layout (bytes)
    const size_t G_ELEMS  = (size_t)SEQ * BATCH * 3 * HID;   // 100663296
    const size_t WR_ELEMS = (size_t)HID * 2 * HID;
    const size_t WO_ELEMS = (size_t)HID * HID;
    char* ws = (char*)d_ws;
    size_t off = 0;
    __bf16* G   = (__bf16*)(ws + off); off += G_ELEMS * 2;
    __bf16* Wrb = (__bf16*)(ws + off); off += WR_ELEMS * 2;
    __bf16* Wub = (__bf16*)(ws + off); off += WR_ELEMS * 2;
    __bf16* Wob = (__bf16*)(ws + off); off += WO_ELEMS * 2;
    __bf16* Wxb = (__bf16*)(ws + off); off += WO_ELEMS * 2;
    __bf16* hg  = (__bf16*)(ws + off); off += (size_t)2 * BATCH * HID * 2;
    unsigned* cnt = (unsigned*)(ws + off); off += 256;
    const size_t X_ELEMS = (size_t)SEQ * BATCH * HID;
    bool use_xb = (ws_size >= off + X_ELEMS * 2);
    __bf16* xb = (__bf16*)(ws + off);

    // conversions
    cvt_f32_bf16<<<(int)(WR_ELEMS / 4 / 256), 256, 0, stream>>>(Wr, Wrb, (int)WR_ELEMS);
    cvt_f32_bf16<<<(int)(WR_ELEMS / 4 / 256), 256, 0, stream>>>(Wu, Wub, (int)WR_ELEMS);
    cvt_f32_bf16<<<(int)(WO_ELEMS / 4 / 256), 256, 0, stream>>>(Wo, Wob, (int)WO_ELEMS);
    cvt_f32_bf16<<<(int)(WO_ELEMS / 4 / 256), 256, 0, stream>>>(Wx, Wxb, (int)WO_ELEMS);
    if (use_xb)
        cvt_f32_bf16<<<(int)(X_ELEMS / 4 / 256), 256, 0, stream>>>(x, xb, (int)X_ELEMS);

    gru_init<<<(BATCH * HID) / 256, 256, 0, stream>>>(prev, hg, cnt);

    int gridA = (SEQ * BATCH / 128) * ((3 * HID) / 64);
    if (use_xb)
        gru_phaseA<true><<<gridA, 256, 0, stream>>>(x, xb, Wrb, Wub, Wxb, br, bu, bx, G);
    else
        gru_phaseA<false><<<gridA, 256, 0, stream>>>(x, xb, Wrb, Wub, Wxb, br, bu, bx, G);

    const size_t LDS_B = 48 * 1024 * 2 + 12288 + 4096;  // 114688 B
    gru_phaseB<<<HID / 16, 768, LDS_B, stream>>>(Wrb, Wub, Wob, bo, prev, G, hg, cnt, out);
}

// Round 4
// 4799.848 us; speedup vs baseline: 2.5195x; 1.9202x over previous
//
#include <hip/hip_runtime.h>
#include <hip/hip_bf16.h>

#define SEQ 512
#define BATCH 64
#define HID 1024

typedef __bf16 bf16x8 __attribute__((ext_vector_type(8)));
typedef __bf16 bf16x4 __attribute__((ext_vector_type(4)));
typedef float f32x4 __attribute__((ext_vector_type(4)));

__device__ __forceinline__ float sigm(float x) { return 1.0f / (1.0f + __expf(-x)); }
__device__ __forceinline__ float tanh_(float x) { return 2.0f / (1.0f + __expf(-2.0f * x)) - 1.0f; }

// ---- device-coherent (LLC coherence point) access helpers ----
__device__ __forceinline__ void cload_b128(bf16x8* d, const __bf16* p) {
    asm volatile("global_load_dwordx4 %0, %1, off sc0 sc1" : "=v"(*d) : "v"(p));
}
__device__ __forceinline__ void cstore_b16(__bf16* p, __bf16 v) {
    unsigned short uv = __builtin_bit_cast(unsigned short, v);
    asm volatile("global_store_short %0, %1, off sc0 sc1" :: "v"(p), "v"(uv));
}
__device__ __forceinline__ void cstore_b32(unsigned* p, unsigned v) {
    asm volatile("global_store_dword %0, %1, off sc0 sc1" :: "v"(p), "v"(v));
}
__device__ __forceinline__ unsigned cload_b32(const unsigned* p) {
    unsigned r;
    asm volatile("global_load_dword %0, %1, off sc0 sc1\n\ts_waitcnt vmcnt(0)"
                 : "=v"(r) : "v"(p) : "memory");
    __builtin_amdgcn_sched_barrier(0);
    return r;
}
__device__ __forceinline__ void vmcnt0() {
    asm volatile("s_waitcnt vmcnt(0)" ::: "memory");
    __builtin_amdgcn_sched_barrier(0);
}

// ---------------------------------------------------------------------------
// f32 -> bf16 conversion (n multiple of 4)
// ---------------------------------------------------------------------------
__global__ __launch_bounds__(256) void cvt_f32_bf16(const float* __restrict__ src,
                                                     __bf16* __restrict__ dst, int n)
{
    int i = (blockIdx.x * 256 + threadIdx.x) * 4;
    if (i < n) {
        f32x4 v = *(const f32x4*)(src + i);
        bf16x4 o;
        #pragma unroll
        for (int j = 0; j < 4; ++j) o[j] = (__bf16)v[j];
        *(bf16x4*)(dst + i) = o;
    }
}

// ---------------------------------------------------------------------------
// Phase A (unchanged): G[m][n] = x-parts of gates, m = t*BATCH+b.
// ---------------------------------------------------------------------------
template <bool XB>
__global__ __launch_bounds__(256) void gru_phaseA(
    const float* __restrict__ xf, const __bf16* __restrict__ xb,
    const __bf16* __restrict__ Wrb, const __bf16* __restrict__ Wub,
    const __bf16* __restrict__ Wxb,
    const float* __restrict__ br, const float* __restrict__ bu,
    const float* __restrict__ bx, __bf16* __restrict__ G)
{
    const int NT = (3 * HID) / 64;
    int mt = blockIdx.x / NT;
    int nt = blockIdx.x % NT;
    int m0 = mt * 128, n0 = nt * 64;

    const __bf16* W; const float* bias; int wstride, nb;
    if (n0 < HID)          { W = Wrb; bias = br; wstride = 2 * HID; nb = n0; }
    else if (n0 < 2 * HID) { W = Wub; bias = bu; wstride = 2 * HID; nb = n0 - HID; }
    else                   { W = Wxb; bias = bx; wstride = HID;     nb = n0 - 2 * HID; }

    int lane = threadIdx.x & 63, w = threadIdx.x >> 6;
    int llo = lane & 15, lhi = lane >> 4;
    int wm = (w & 1) * 64, wn = (w >> 1) * 32;

    f32x4 acc[4][2] = {};
    #pragma unroll 2
    for (int k0 = 0; k0 < HID; k0 += 32) {
        int ka = k0 + lhi * 8;
        bf16x8 af[4], bfr[2];
        #pragma unroll
        for (int mi = 0; mi < 4; ++mi) {
            size_t roff = (size_t)(m0 + wm + mi * 16 + llo) * HID + ka;
            if (XB) {
                af[mi] = *(const bf16x8*)(xb + roff);
            } else {
                f32x4 lo = *(const f32x4*)(xf + roff);
                f32x4 hi = *(const f32x4*)(xf + roff + 4);
                #pragma unroll
                for (int jj = 0; jj < 4; ++jj) { af[mi][jj] = (__bf16)lo[jj]; af[mi][4 + jj] = (__bf16)hi[jj]; }
            }
        }
        #pragma unroll
        for (int ni = 0; ni < 2; ++ni)
            bfr[ni] = *(const bf16x8*)(W + (size_t)(nb + wn + ni * 16 + llo) * wstride + ka);
        #pragma unroll
        for (int mi = 0; mi < 4; ++mi)
            #pragma unroll
            for (int ni = 0; ni < 2; ++ni)
                acc[mi][ni] = __builtin_amdgcn_mfma_f32_16x16x32_bf16(af[mi], bfr[ni], acc[mi][ni], 0, 0, 0);
    }
    #pragma unroll
    for (int ni = 0; ni < 2; ++ni) {
        int colg = n0 + wn + ni * 16 + llo;
        float bv = bias[nb + wn + ni * 16 + llo];
        #pragma unroll
        for (int mi = 0; mi < 4; ++mi) {
            #pragma unroll
            for (int i = 0; i < 4; ++i) {
                int row = m0 + wm + mi * 16 + lhi * 4 + i;
                G[(size_t)row * (3 * HID) + colg] = (__bf16)(acc[mi][ni][i] + bv);
            }
        }
    }
}

// ---------------------------------------------------------------------------
// Init: hg[0] = bf16(prev); zero per-WG barrier flags.
// ---------------------------------------------------------------------------
__global__ __launch_bounds__(256) void gru_init(const float* __restrict__ prev,
                                                __bf16* __restrict__ hg,
                                                unsigned* __restrict__ flags)
{
    int i = blockIdx.x * 256 + threadIdx.x;
    if (i < 64 * 32) flags[i] = 0u;
    if (i < BATCH * HID) hg[i] = (__bf16)prev[i];
}

// ---------------------------------------------------------------------------
// Phase B v3: persistent recurrent kernel, fence-free.
// 64 WGs x 768 threads (12 waves). WG j owns hidden cols [16j,16j+16).
// - Weights (48 gate-rows x 1024) in LDS, XOR-swizzled, staged once (96KB).
// - 12 compute waves = 4 row-groups x 3 K-splits; each computes ALL 3 gates
//   over its K third -> partials in gbuf (36KB). Cuts coherent-h traffic 3x.
// - h exchange via sc0/sc1 (device-coherent, LLC) loads/stores ONLY -> no
//   threadfence, L2 never invalidated; G/weights/out stay cached.
// - Barrier: per-WG flag (128B stride) store after vmcnt(0); wave 0 polls all
//   64 flags with one coherent load per lane + __all. No atomics.
// LDS: 96KB W + 36KB gbuf + 4KB hm = 136KB -> 1 WG/CU.
// ---------------------------------------------------------------------------
__global__ __launch_bounds__(768) void gru_phaseB(
    const __bf16* __restrict__ Wrb, const __bf16* __restrict__ Wub,
    const __bf16* __restrict__ Wob, const float* __restrict__ bo,
    const float* __restrict__ prev, const __bf16* __restrict__ G,
    __bf16* __restrict__ hg, unsigned* __restrict__ flags,
    float* __restrict__ out)
{
    extern __shared__ char smem[];
    __bf16* Wl   = (__bf16*)smem;                              // [48][1024] swizzled
    float*  gbuf = (float*)(smem + 48 * 1024 * 2);             // [3][4][3][64][4]
    float*  hm   = (float*)(smem + 48 * 1024 * 2 + 36864);     // [64][16]

    const int j = blockIdx.x;           // 0..63
    const int tid = threadIdx.x;
    const int lane = tid & 63, w = tid >> 6;
    const int llo = lane & 15, lhi = lane >> 4;

    // ---- stage weights into LDS (once), XOR-swizzled ----
    {
        int R = tid >> 4;            // 0..47  (gate*16 + col-within-16)
        int seg = tid & 15;          // 0..15
        int gg = R >> 4, c = R & 15;
        const __bf16* src;
        if (gg == 0)      src = Wrb + (size_t)(16 * j + c) * (2 * HID) + HID;
        else if (gg == 1) src = Wub + (size_t)(16 * j + c) * (2 * HID) + HID;
        else              src = Wob + (size_t)(16 * j + c) * HID;
        #pragma unroll
        for (int q = 0; q < 8; ++q) {
            int k = seg * 64 + q * 8;
            bf16x8 v = *(const bf16x8*)(src + k);
            int byte = R * 2048 + k * 2;
            byte ^= ((R & 7) << 4);
            *(bf16x8*)((char*)Wl + byte) = v;
        }
    }
    // ---- init h fp32 master (this WG's 16 cols) ----
    for (int m = tid; m < BATCH * 16; m += 768) {
        int r = m >> 4, c = m & 15;
        hm[m] = prev[(size_t)r * HID + 16 * j + c];
    }
    __syncthreads();

    // gate-combine wave state (waves 0..3)
    float bov = 0.f;
    float pr[4], pu[4], px[4], outv[4];
    if (w < 4) {
        bov = bo[16 * j + llo];
        #pragma unroll
        for (int i = 0; i < 4; ++i) {
            int row = 16 * w + lhi * 4 + i;
            const __bf16* Gp = G + (size_t)row * (3 * HID) + 16 * j + llo;
            pr[i] = (float)Gp[0]; pu[i] = (float)Gp[HID]; px[i] = (float)Gp[2 * HID];
        }
    }

    const int rg = w & 3, ks = w >> 2;   // compute role: row-group x K-split
    const int swz = ((llo & 7) << 4);

    for (int t = 0; t < SEQ; ++t) {
        const __bf16* hcur = hg + (size_t)(t & 1) * (BATCH * HID);
        __bf16* hnxt = hg + (size_t)((t + 1) & 1) * (BATCH * HID);

        // ---- compute partials: all 3 gates over this wave's K third ----
        {
            const __bf16* hrow = hcur + (size_t)(16 * rg + llo) * HID;
            bf16x8 hv[11];
            #pragma unroll
            for (int q = 0; q < 11; ++q) {
                int it = ks + 3 * q;
                if (it < 32) cload_b128(&hv[q], hrow + it * 32 + lhi * 8);
            }
            vmcnt0();
            f32x4 aR = {}, aU = {}, aO = {};
            #pragma unroll
            for (int q = 0; q < 11; ++q) {
                int it = ks + 3 * q;
                if (it < 32) {
                    int kb = it * 64 + lhi * 16;
                    bf16x8 bR = *(const bf16x8*)((const char*)Wl + (((0 * 16 + llo) * 2048 + kb) ^ swz));
                    bf16x8 bU = *(const bf16x8*)((const char*)Wl + (((1 * 16 + llo) * 2048 + kb) ^ swz));
                    bf16x8 bO = *(const bf16x8*)((const char*)Wl + (((2 * 16 + llo) * 2048 + kb) ^ swz));
                    aR = __builtin_amdgcn_mfma_f32_16x16x32_bf16(hv[q], bR, aR, 0, 0, 0);
                    aU = __builtin_amdgcn_mfma_f32_16x16x32_bf16(hv[q], bU, aU, 0, 0, 0);
                    aO = __builtin_amdgcn_mfma_f32_16x16x32_bf16(hv[q], bO, aO, 0, 0, 0);
                }
            }
            *(f32x4*)(gbuf + (((0 * 4 + rg) * 3 + ks) * 64 + lane) * 4) = aR;
            *(f32x4*)(gbuf + (((1 * 4 + rg) * 3 + ks) * 64 + lane) * 4) = aU;
            *(f32x4*)(gbuf + (((2 * 4 + rg) * 3 + ks) * 64 + lane) * 4) = aO;
        }
        __syncthreads();   // sync1: gbuf ready

        if (w < 4) {
            f32x4 aR = {}, aU = {}, aO = {};
            #pragma unroll
            for (int kk = 0; kk < 3; ++kk) {
                aR += *(const f32x4*)(gbuf + (((0 * 4 + w) * 3 + kk) * 64 + lane) * 4);
                aU += *(const f32x4*)(gbuf + (((1 * 4 + w) * 3 + kk) * 64 + lane) * 4);
                aO += *(const f32x4*)(gbuf + (((2 * 4 + w) * 3 + kk) * 64 + lane) * 4);
            }
            #pragma unroll
            for (int i = 0; i < 4; ++i) {
                int row = 16 * w + lhi * 4 + i;
                float r = sigm(aR[i] + pr[i]);
                float u = sigm(aU[i] + pu[i]);
                float c = tanh_((aO[i] + bov) * r + px[i]);
                float hold = hm[row * 16 + llo];
                float hnew = (1.0f - u) * c + u * hold;
                hm[row * 16 + llo] = hnew;
                cstore_b16(hnxt + (size_t)row * HID + 16 * j + llo, (__bf16)hnew);
                outv[i] = hnew;
            }
            vmcnt0();      // h writes at coherence point before flag
        }
        __syncthreads();   // sync2: whole WG's h published

        if (w == 0 && lane == 0) cstore_b32(flags + j * 32, (unsigned)(t + 1));
        // deferred work overlaps other WGs' polling
        if (w < 4) {
            #pragma unroll
            for (int i = 0; i < 4; ++i) {
                int row = 16 * w + lhi * 4 + i;
                __builtin_nontemporal_store(outv[i],
                    out + (size_t)t * (BATCH * HID) + (size_t)row * HID + 16 * j + llo);
                if (t == SEQ - 1)
                    __builtin_nontemporal_store(outv[i],
                        out + (size_t)SEQ * (BATCH * HID) + (size_t)row * HID + 16 * j + llo);
            }
            if (t + 1 < SEQ) {
                const __bf16* Gt = G + (size_t)(t + 1) * BATCH * (3 * HID);
                #pragma unroll
                for (int i = 0; i < 4; ++i) {
                    int row = 16 * w + lhi * 4 + i;
                    const __bf16* Gp = Gt + (size_t)row * (3 * HID) + 16 * j + llo;
                    pr[i] = (float)Gp[0]; pu[i] = (float)Gp[HID]; px[i] = (float)Gp[2 * HID];
                }
            }
        }
        if (w == 0) {
            const unsigned* mp = flags + lane * 32;
            int guard = 0;
            unsigned v;
            do {
                v = cload_b32(mp);
                if (__all((int)(v >= (unsigned)(t + 1)))) break;
                __builtin_amdgcn_s_sleep(2);
            } while (++guard < (1 << 20));
        }
        __syncthreads();   // sync3: step complete everywhere
    }
}

extern "C" void kernel_launch(void* const* d_in, const int* in_sizes, int n_in,
                              void* d_out, int out_size, void* d_ws, size_t ws_size,
                              hipStream_t stream) {
    (void)in_sizes; (void)n_in; (void)out_size;
    const float* x    = (const float*)d_in[0];
    const float* prev = (const float*)d_in[1];
    const float* Wr   = (const float*)d_in[2];
    const float* br   = (const float*)d_in[3];
    const float* Wu   = (const float*)d_in[4];
    const float* bu   = (const float*)d_in[5];
    const float* Wo   = (const float*)d_in[6];
    const float* bo   = (const float*)d_in[7];
    const float* Wx   = (const float*)d_in[8];
    const float* bx   = (const float*)d_in[9];
    float* out = (float*)d_out;

    // workspace layout (bytes)
    const size_t G_ELEMS  = (size_t)SEQ * BATCH * 3 * HID;
    const size_t WR_ELEMS = (size_t)HID * 2 * HID;
    const size_t WO_ELEMS = (size_t)HID * HID;
    char* ws = (char*)d_ws;
    size_t off = 0;
    __bf16* G   = (__bf16*)(ws + off); off += G_ELEMS * 2;
    __bf16* Wrb = (__bf16*)(ws + off); off += WR_ELEMS * 2;
    __bf16* Wub = (__bf16*)(ws + off); off += WR_ELEMS * 2;
    __bf16* Wob = (__bf16*)(ws + off); off += WO_ELEMS * 2;
    __bf16* Wxb = (__bf16*)(ws + off); off += WO_ELEMS * 2;
    __bf16* hg  = (__bf16*)(ws + off); off += (size_t)2 * BATCH * HID * 2;
    unsigned* flags = (unsigned*)(ws + off); off += 64 * 32 * 4;   // 8KB, 128B-strided
    const size_t X_ELEMS = (size_t)SEQ * BATCH * HID;
    bool use_xb = (ws_size >= off + X_ELEMS * 2);
    __bf16* xb = (__bf16*)(ws + off);

    // conversions
    cvt_f32_bf16<<<(int)(WR_ELEMS / 4 / 256), 256, 0, stream>>>(Wr, Wrb, (int)WR_ELEMS);
    cvt_f32_bf16<<<(int)(WR_ELEMS / 4 / 256), 256, 0, stream>>>(Wu, Wub, (int)WR_ELEMS);
    cvt_f32_bf16<<<(int)(WO_ELEMS / 4 / 256), 256, 0, stream>>>(Wo, Wob, (int)WO_ELEMS);
    cvt_f32_bf16<<<(int)(WO_ELEMS / 4 / 256), 256, 0, stream>>>(Wx, Wxb, (int)WO_ELEMS);
    if (use_xb)
        cvt_f32_bf16<<<(int)(X_ELEMS / 4 / 256), 256, 0, stream>>>(x, xb, (int)X_ELEMS);

    gru_init<<<(BATCH * HID) / 256, 256, 0, stream>>>(prev, hg, flags);

    int gridA = (SEQ * BATCH / 128) * ((3 * HID) / 64);
    if (use_xb)
        gru_phaseA<true><<<gridA, 256, 0, stream>>>(x, xb, Wrb, Wub, Wxb, br, bu, bx, G);
    else
        gru_phaseA<false><<<gridA, 256, 0, stream>>>(x, xb, Wrb, Wub, Wxb, br, bu, bx, G);

    const size_t LDS_B = 48 * 1024 * 2 + 36864 + 4096;  // 139264 B
    gru_phaseB<<<HID / 16, 768, LDS_B, stream>>>(Wrb, Wub, Wob, bo, prev, G, hg, flags, out);
}